// Round 5
// baseline (500.893 us; speedup 1.0000x reference)
//
#include <hip/hip_runtime.h>

// GCN via CSR pull-aggregation, float4-vectorized.
// CSR build uses dst-range-partitioned histogram/scatter: blocks with
// blockIdx&7==r handle only dst in [r*N/8,(r+1)*N/8) so each XCD's L2 holds a
// 1.25MB adj slice (+cursor/R slices); the 8x re-read of the edge list uses
// nontemporal loads so the stream doesn't evict the resident slices.

constexpr int H = 32;
constexpr int POOL_CHUNK = 1024;
constexpr int NR = 8;                 // dst ranges == XCD count

// ---- CSR build ----
__global__ void hist_kernel(const int* __restrict__ dst, int* __restrict__ cnt, int N, int E) {
    const int r = blockIdx.x & (NR - 1);
    const int b = blockIdx.x >> 3;
    const int nb = gridDim.x >> 3;
    const int lo = (int)((long long)r * N / NR);
    const int hi = (int)((long long)(r + 1) * N / NR);
    const int stride = nb * blockDim.x;
    for (int e = b * blockDim.x + threadIdx.x; e < E; e += stride) {
        int v = __builtin_nontemporal_load(&dst[e]);
        if (v >= lo && v < hi) atomicAdd(&cnt[v], 1);
    }
}

// scan1: in-place exclusive scan of 1024-element chunks of R; block totals -> bsum.
// Also emits dinv[i] = rsqrt(count_i + 1) while counts are in registers.
__global__ void scan1_kernel(int* __restrict__ R, int* __restrict__ bsum,
                             float* __restrict__ dinv, int N) {
    __shared__ int sh[256];
    int base = blockIdx.x * 1024 + threadIdx.x * 4;
    int v[4]; int s = 0;
#pragma unroll
    for (int q = 0; q < 4; q++) {
        int idx = base + q;
        v[q] = (idx < N) ? R[idx] : 0;
        if (idx < N) dinv[idx] = rsqrtf((float)v[q] + 1.0f);
        s += v[q];
    }
    sh[threadIdx.x] = s;
    __syncthreads();
    for (int off = 1; off < 256; off <<= 1) {
        int t = (threadIdx.x >= off) ? sh[threadIdx.x - off] : 0;
        __syncthreads();
        sh[threadIdx.x] += t;
        __syncthreads();
    }
    int excl = sh[threadIdx.x] - s;
#pragma unroll
    for (int q = 0; q < 4; q++) { int idx = base + q; if (idx < N) R[idx] = excl; excl += v[q]; }
    if (threadIdx.x == 255) bsum[blockIdx.x] = sh[255];
}

__global__ void scan2_kernel(int* __restrict__ bsum, int nb) {
    __shared__ int sh[1024];
    int t = threadIdx.x;
    int orig = (t < nb) ? bsum[t] : 0;
    sh[t] = orig;
    __syncthreads();
    for (int off = 1; off < 1024; off <<= 1) {
        int v = (t >= off) ? sh[t - off] : 0;
        __syncthreads();
        sh[t] += v;
        __syncthreads();
    }
    if (t < nb) bsum[t] = sh[t] - orig;
}

__global__ void scan3_kernel(int* __restrict__ R, const int* __restrict__ bsum, int N) {
    int i = blockIdx.x * blockDim.x + threadIdx.x;
    if (i < N) R[i] += bsum[i >> 10];
}

__global__ void scatter_kernel(const int* __restrict__ src, const int* __restrict__ dst,
                               const int* __restrict__ R, int* __restrict__ cursor,
                               int* __restrict__ adj, int N, int E) {
    const int r = blockIdx.x & (NR - 1);
    const int b = blockIdx.x >> 3;
    const int nb = gridDim.x >> 3;
    const int lo = (int)((long long)r * N / NR);
    const int hi = (int)((long long)(r + 1) * N / NR);
    const int stride = nb * blockDim.x;
    for (int e = b * blockDim.x + threadIdx.x; e < E; e += stride) {
        int v = __builtin_nontemporal_load(&dst[e]);
        if (v >= lo && v < hi) {
            int pos = R[v] + atomicAdd(&cursor[v], 1);
            adj[pos] = __builtin_nontemporal_load(&src[e]);
        }
    }
}

// ---- lin1: S[i][4q..4q+3] = dinv[i] * x[i] @ W1[:,4q..4q+3], coalesced float4 stores
__global__ void lin1_kernel(const float* __restrict__ x, const float4* __restrict__ W1v,
                            const float* __restrict__ dinv, float4* __restrict__ S, int N) {
    int t = blockIdx.x * blockDim.x + threadIdx.x;
    int i = t >> 3, q = t & 7;
    if (i >= N) return;
    float di = dinv[i];
    float4 o = make_float4(0.f, 0.f, 0.f, 0.f);
#pragma unroll
    for (int k = 0; k < 5; k++) {
        float xv = x[i * 5 + k];
        float4 w = W1v[k * 8 + q];            // W1[k][4q..4q+3]
        o.x = fmaf(xv, w.x, o.x); o.y = fmaf(xv, w.y, o.y);
        o.z = fmaf(xv, w.z, o.z); o.w = fmaf(xv, w.w, o.w);
    }
    o.x *= di; o.y *= di; o.z *= di; o.w *= di;
    S[(size_t)i * 8 + q] = o;
}

// ---- pull: val[i][q] = RELU?( dinv*(self + sum_nbr) + bias );
// FUSE_W2: Sout[i] = dinv[i] * (val_row @ W2) via LDS row exchange.
template<int RELU, int FUSE_W2>
__global__ void pull_kernel(const float4* __restrict__ Sin, const int* __restrict__ R,
                            const int* __restrict__ adj, const float* __restrict__ dinv,
                            const float* __restrict__ bias, const float4* __restrict__ W2v,
                            float4* __restrict__ Sout, int N, int E) {
    __shared__ float hsh[32][33];   // 32 node rows, +1 pad
    __shared__ float4 wsh[32][8];   // W2: wsh[k][q] = W2[k][4q..4q+3]
    int t = blockIdx.x * blockDim.x + threadIdx.x;
    int i = t >> 3, q = t & 7;
    if (FUSE_W2) {
        wsh[threadIdx.x >> 3][threadIdx.x & 7] = W2v[threadIdx.x];  // 256 float4 = full W2
    }
    bool active = (i < N);
    float4 val = make_float4(0.f, 0.f, 0.f, 0.f);
    float di = 0.f;
    if (active) {
        float4 acc = Sin[(size_t)i * 8 + q];            // self-loop
        int s = __builtin_nontemporal_load(&R[i]);
        int e2 = (i == N - 1) ? E : __builtin_nontemporal_load(&R[i + 1]);
        for (int k = s; k < e2; k++) {
            int u = __builtin_nontemporal_load(&adj[k]);
            float4 v = Sin[(size_t)u * 8 + q];
            acc.x += v.x; acc.y += v.y; acc.z += v.z; acc.w += v.w;
        }
        di = dinv[i];
        float4 b = bias ? make_float4(bias[q*4], bias[q*4+1], bias[q*4+2], bias[q*4+3])
                        : make_float4(0.f, 0.f, 0.f, 0.f);
        val.x = fmaf(di, acc.x, b.x); val.y = fmaf(di, acc.y, b.y);
        val.z = fmaf(di, acc.z, b.z); val.w = fmaf(di, acc.w, b.w);
        if (RELU) {
            val.x = fmaxf(val.x, 0.f); val.y = fmaxf(val.y, 0.f);
            val.z = fmaxf(val.z, 0.f); val.w = fmaxf(val.w, 0.f);
        }
    }
    if constexpr (FUSE_W2) {
        int local = threadIdx.x >> 3;
        if (active) {
            hsh[local][q * 4 + 0] = val.x; hsh[local][q * 4 + 1] = val.y;
            hsh[local][q * 4 + 2] = val.z; hsh[local][q * 4 + 3] = val.w;
        }
        __syncthreads();
        if (active) {
            float4 o = make_float4(0.f, 0.f, 0.f, 0.f);
#pragma unroll
            for (int k = 0; k < H; k++) {
                float hk = hsh[local][k];
                float4 w = wsh[k][q];
                o.x = fmaf(hk, w.x, o.x); o.y = fmaf(hk, w.y, o.y);
                o.z = fmaf(hk, w.z, o.z); o.w = fmaf(hk, w.w, o.w);
            }
            o.x *= di; o.y *= di; o.z *= di; o.w *= di;
            Sout[(size_t)i * 8 + q] = o;
        }
    } else {
        if (active) Sout[(size_t)i * 8 + q] = val;
    }
}

// ---- pooling ----
__global__ void bounds_kernel(const int* __restrict__ batch, int* __restrict__ startg,
                              int* __restrict__ endg, int N) {
    int i = blockIdx.x * blockDim.x + threadIdx.x;
    if (i >= N) return;
    int g = batch[i];
    if (i == 0 || batch[i - 1] != g) startg[g] = i;
    if (i == N - 1 || batch[i + 1] != g) endg[g] = i + 1;
}

// segmented sum over sorted batch; one atomic flush per (run x thread), float4 reads
__global__ void pool_kernel(const float4* __restrict__ H2, const int* __restrict__ batch,
                            float* __restrict__ pooled, int N) {
    const int q = threadIdx.x & 7;
    const int r = threadIdx.x >> 3;        // 0..31 rows in flight
    const int ROWS = 32;
    long long base = (long long)blockIdx.x * POOL_CHUNK;
    long long end = base + POOL_CHUNK;
    if (end > N) end = N;
    float4 acc = make_float4(0.f, 0.f, 0.f, 0.f);
    int cur_g = -1;
    for (long long i = base + r; i < end; i += ROWS) {
        int g = batch[i];
        float4 v = H2[i * 8 + q];
        if (g != cur_g) {
            if (cur_g >= 0) {
                float* p = &pooled[(size_t)cur_g * H + q * 4];
                atomicAdd(p + 0, acc.x); atomicAdd(p + 1, acc.y);
                atomicAdd(p + 2, acc.z); atomicAdd(p + 3, acc.w);
            }
            acc = make_float4(0.f, 0.f, 0.f, 0.f);
            cur_g = g;
        }
        acc.x += v.x; acc.y += v.y; acc.z += v.z; acc.w += v.w;
    }
    if (cur_g >= 0) {
        float* p = &pooled[(size_t)cur_g * H + q * 4];
        atomicAdd(p + 0, acc.x); atomicAdd(p + 1, acc.y);
        atomicAdd(p + 2, acc.z); atomicAdd(p + 3, acc.w);
    }
}

// out[g] = (pooled[g]/cnt + b2) @ Wfc + bfc   (b2 commutes through mean)
__global__ void final_kernel(const float* __restrict__ pooled, const int* __restrict__ startg,
                             const int* __restrict__ endg, const float* __restrict__ b2,
                             const float* __restrict__ Wfc, const float* __restrict__ bfc,
                             float* __restrict__ out, int G) {
    int g = blockIdx.x * blockDim.x + threadIdx.x;
    if (g >= G) return;
    float cnt = (float)(endg[g] - startg[g]);
    float inv = 1.0f / fmaxf(cnt, 1.0f);
    float s0 = 0.f, s1 = 0.f;
#pragma unroll
    for (int j = 0; j < H; j++) {
        float p = fmaf(pooled[g * H + j], inv, b2[j]);
        s0 = fmaf(p, Wfc[j * 2 + 0], s0);
        s1 = fmaf(p, Wfc[j * 2 + 1], s1);
    }
    out[g * 2 + 0] = s0 + bfc[0];
    out[g * 2 + 1] = s1 + bfc[1];
}

extern "C" void kernel_launch(void* const* d_in, const int* in_sizes, int n_in,
                              void* d_out, int out_size, void* d_ws, size_t ws_size,
                              hipStream_t stream) {
    const float* x    = (const float*)d_in[0];
    const float* W1   = (const float*)d_in[1];
    const float* b1   = (const float*)d_in[2];
    const float* W2   = (const float*)d_in[3];
    const float* b2   = (const float*)d_in[4];
    const float* Wfc  = (const float*)d_in[5];
    const float* bfc  = (const float*)d_in[6];
    const int*   eidx = (const int*)d_in[7];
    const int*   batch= (const int*)d_in[8];
    float* out = (float*)d_out;

    const int N = in_sizes[0] / 5;
    const int E = in_sizes[7] / 2;
    const int G = out_size / 2;

    const int* src = eidx;
    const int* dst = eidx + E;

    char* ws = (char*)d_ws;
    size_t off = 0;
    auto alloc = [&](size_t bytes) { char* p = ws + off; off = (off + bytes + 255) & ~(size_t)255; return p; };
    size_t Npad = ((size_t)N * 4 + 255) & ~(size_t)255;
    int*   R      = (int*)alloc((size_t)N * 4);          // counts -> rowptr (in place)
    int*   cursor = (int*)alloc((size_t)N * 4);          // contiguous with R
    int*   adj    = (int*)alloc((size_t)E * 4);
    int*   bsum   = (int*)alloc(4096);
    float* dinv   = (float*)alloc((size_t)N * 4);
    float* S1     = (float*)alloc((size_t)N * H * 4);
    float* S2     = (float*)alloc((size_t)N * H * 4);
    float* pooled = (float*)alloc((size_t)G * H * 4);    // pooled/startg/endg contiguous
    int*   startg = (int*)alloc((size_t)G * 4);
    int*   endg   = (int*)alloc((size_t)G * 4);
    (void)ws_size;

    const int T = 256;
    auto nb = [&](long long n) { return (int)((n + T - 1) / T); };
    const int nscan = (N + 1023) / 1024;   // 489 for N=500k (must be <= 1024)

    hipMemsetAsync(R, 0, Npad * 2, stream);                                   // R + cursor
    hipMemsetAsync(pooled, 0, (size_t)G * H * 4 + (size_t)G * 4 * 2, stream); // pooled+startg+endg

    // CSR build (range-partitioned hist/scatter; dinv fused into scan1)
    hist_kernel<<<2048, T, 0, stream>>>(dst, R, N, E);
    scan1_kernel<<<nscan, 256, 0, stream>>>(R, bsum, dinv, N);
    scan2_kernel<<<1, 1024, 0, stream>>>(bsum, nscan);
    scan3_kernel<<<nb(N), T, 0, stream>>>(R, bsum, N);
    scatter_kernel<<<2048, T, 0, stream>>>(src, dst, R, cursor, adj, N, E);

    // layer 1 (+ fused W2 transform)
    lin1_kernel<<<nb((long long)N * 8), T, 0, stream>>>(x, (const float4*)W1, dinv, (float4*)S1, N);
    pull_kernel<1, 1><<<nb((long long)N * 8), T, 0, stream>>>(
        (const float4*)S1, R, adj, dinv, b1, (const float4*)W2, (float4*)S2, N, E);

    // layer 2
    pull_kernel<0, 0><<<nb((long long)N * 8), T, 0, stream>>>(
        (const float4*)S2, R, adj, dinv, nullptr, nullptr, (float4*)S1, N, E);

    // pool + fc
    bounds_kernel<<<nb(N), T, 0, stream>>>(batch, startg, endg, N);
    pool_kernel<<<(N + POOL_CHUNK - 1) / POOL_CHUNK, T, 0, stream>>>(
        (const float4*)S1, batch, pooled, N);
    final_kernel<<<nb(G), T, 0, stream>>>(pooled, startg, endg, b2, Wfc, bfc, out, G);
}